// Round 6
// baseline (177.794 us; speedup 1.0000x reference)
//
#include <hip/hip_runtime.h>
#include <math.h>

#define N_SAMP   32768
#define WINDOW   512
#define STEP     256
#define NFRAMES  127      // (32768-512)/256 + 1
#define NB       4
#define RTRUNC   1280     // h truncation radius (samples)
#define NSLAB    32       // R16 best-measured config
#define BPAD     776      // B-copy stride (elems): 388 words = 4 mod 32 banks
#define HW       3104     // per-frame h window (floats), 776 float4 blocks
#define VSTRIDE  193      // k_vmax per-wave region stride (blocks)

// ws layout (float granularity)
#define WS_WF   0               // 4*127*512 = 260096 floats (fp32, shift conv)
#define WS_WFH  260096          // 4*64*128*8 fp16 = 131072 float slots (k-major)
#define WS_WFL  391168          // 131072 (reserved: absorbs A prefetch overrun)
#define WS_PV   522240          // 4*128*128 = 65536 (per-chunk fp16 max)
#define WS_M    587776          // 512 ints (argmax per (b,f))
#define WS_CNT  588288          // 16 ints
#define WS_LIST 588304          // 4096 ints (entry list)
#define WS_H    592400          // 508*3104 = 1576832 floats (truncated sinc)
#define WS_PART 2169232         // nslab*4*32768 floats (per-slot partials)

typedef _Float16 f16x8 __attribute__((ext_vector_type(8)));
typedef float f32x16 __attribute__((ext_vector_type(16)));

// XOR swizzle on float4-block index (conflict-free sliding reads)
#define SW(L) ((L) ^ (((L) >> 3) & 7))

#define FMA4(A, LO, HI)                                           \
    A.x = fmaf(c.x, HI.x, A.x); A.x = fmaf(c.y, LO.w, A.x);       \
    A.x = fmaf(c.z, LO.z, A.x); A.x = fmaf(c.w, LO.y, A.x);       \
    A.y = fmaf(c.x, HI.y, A.y); A.y = fmaf(c.y, HI.x, A.y);       \
    A.y = fmaf(c.z, LO.w, A.y); A.y = fmaf(c.w, LO.z, A.y);       \
    A.z = fmaf(c.x, HI.z, A.z); A.z = fmaf(c.y, HI.y, A.z);       \
    A.z = fmaf(c.z, HI.x, A.z); A.z = fmaf(c.w, LO.w, A.z);       \
    A.w = fmaf(c.x, HI.w, A.w); A.w = fmaf(c.y, HI.z, A.w);       \
    A.w = fmaf(c.z, HI.y, A.w); A.w = fmaf(c.w, HI.x, A.w);

// ---------------------------------------------------------------- kernel A
__global__ __launch_bounds__(256) void k_wf(const float* __restrict__ recon,
                                            float* __restrict__ wf,
                                            _Float16* __restrict__ wfh) {
    int e = blockIdx.x * 256 + threadIdx.x;    // 4*128*512 exactly
    int w     = e & 511;
    int bf128 = e >> 9;
    int f = bf128 & 127;
    int b = bf128 >> 7;
    float val = 0.f;
    if (f < NFRAMES) {
        float ham = 0.54f - 0.46f * (float)cos((double)w * (M_PI / 256.0));
        val = ham * recon[b * N_SAMP + f * STEP + w];
        wf[(b * NFRAMES + f) * 512 + w] = val;
    }
    size_t tr = (((size_t)b * 64 + (w >> 3)) * 128 + f) * 8 + (w & 7);
    wfh[tr] = (_Float16)val;
}

// ---------------------------------------------------------------- kernel B
// fm = wf x Toeplitz(tgt), fp16 32x32x16 MFMA; two M-tiles per wave.
__global__ __launch_bounds__(256, 4) void k_argmax_mfma(
        const float* __restrict__ tgt,
        const _Float16* __restrict__ wfh,
        float* __restrict__ pv) {
    __shared__ _Float16 sbh[8 * BPAD];         // 12416 B
    const int tid   = threadIdx.x;
    const int chunk = blockIdx.x & 127;        // 256-t chunk
    const int half  = (blockIdx.x >> 7) & 1;   // 64-frame group
    const int b     = blockIdx.x >> 8;
    const int T0    = chunk * 256;
    const int TB    = T0 + 255;
    const float* tb = tgt + b * N_SAMP;

    for (int oc = tid; oc < 768; oc += 256) {
        int r = oc / 96, s = oc - r * 96;
        int base = TB - r - 8 * s;
        _Float16 h8[8];
#pragma unroll
        for (int j = 0; j < 8; ++j) {
            int t = base - j;
            h8[j] = (_Float16)((t >= 0) ? tb[t] : 0.0f);
        }
        *(f16x8*)&sbh[r * BPAD + 8 * s] = *(f16x8*)h8;
    }
    __syncthreads();

    const int wv  = tid >> 6;
    const int q   = (tid >> 5) & 1;
    const int cl  = tid & 31;
    const int nt0 = 2 * wv;
    const int rp  = 7 - (cl & 7);
    const _Float16* Ah0 = wfh + ((size_t)b * 64) * 1024 + (half * 64 + cl) * 8;

    f32x16 acc00 = (f32x16)(0.f);
    f32x16 acc01 = (f32x16)(0.f);
    f32x16 acc10 = (f32x16)(0.f);
    f32x16 acc11 = (f32x16)(0.f);

    int off = q * 1024;                        // k-slice q; +2048/iter
    int ea  = rp * BPAD + (255 - 32 * nt0 - cl + 8 * q - rp);
    f16x8 a0  = *(const f16x8*)(Ah0 + off);
    f16x8 a1  = *(const f16x8*)(Ah0 + off + 256);
    f16x8 bh0 = *(const f16x8*)&sbh[ea];
    f16x8 bh1 = *(const f16x8*)&sbh[ea - 32];
#pragma unroll
    for (int k0 = 0; k0 < 512; k0 += 16) {
        f16x8 a0n  = *(const f16x8*)(Ah0 + off + 2048);   // overrun -> wfl slot
        f16x8 a1n  = *(const f16x8*)(Ah0 + off + 2304);
        f16x8 bh0n = *(const f16x8*)&sbh[ea + 16];
        f16x8 bh1n = *(const f16x8*)&sbh[ea - 16];
        acc00 = __builtin_amdgcn_mfma_f32_32x32x16_f16(a0, bh0, acc00, 0, 0, 0);
        acc01 = __builtin_amdgcn_mfma_f32_32x32x16_f16(a0, bh1, acc01, 0, 0, 0);
        acc10 = __builtin_amdgcn_mfma_f32_32x32x16_f16(a1, bh0, acc10, 0, 0, 0);
        acc11 = __builtin_amdgcn_mfma_f32_32x32x16_f16(a1, bh1, acc11, 0, 0, 0);
        a0 = a0n; a1 = a1n; bh0 = bh0n; bh1 = bh1n;
        off += 2048; ea += 16;
    }

    __syncthreads();
    float* sval = (float*)sbh;                 // 64 rows x 4 waves
#pragma unroll
    for (int r = 0; r < 16; ++r) {
        float v0 = fmaxf(acc00[r], acc01[r]);
        float v1 = fmaxf(acc10[r], acc11[r]);
#pragma unroll
        for (int mm = 1; mm <= 16; mm <<= 1) {
            v0 = fmaxf(v0, __shfl_xor(v0, mm));
            v1 = fmaxf(v1, __shfl_xor(v1, mm));
        }
        if (cl == 0) {
            int row = (r & 3) + 8 * (r >> 2) + 4 * q;
            sval[row * 4 + wv]        = v0;
            sval[(32 + row) * 4 + wv] = v1;
        }
    }
    __syncthreads();
    if (tid < 64) {
        float v = fmaxf(fmaxf(sval[tid * 4], sval[tid * 4 + 1]),
                        fmaxf(sval[tid * 4 + 2], sval[tid * 4 + 3]));
        pv[((size_t)b * 128 + half * 64 + tid) * 128 + chunk] = v;
    }
}

// ---------------------------------------------------------------- kernel C
// R20 form: one wave per candidate, FMA4 sliding-block conv, bit-identical
// accumulation order (w2 ascending).
__global__ __launch_bounds__(256) void k_vmax(const float* __restrict__ tgt,
                                              const float* __restrict__ wf,
                                              const float* __restrict__ pv,
                                              int* __restrict__ marr) {
    __shared__ __align__(16) float stg[4 * VSTRIDE * 4];  // 12352 B
    __shared__ float rv[256];
    __shared__ int   ri[256];
    __shared__ int   clist[32];
    __shared__ int   ccnt;
    const int tid  = threadIdx.x;
    const int lane = tid & 63;
    const int wv   = tid >> 6;
    const int fr   = blockIdx.x;
    const int b    = fr / NFRAMES;
    const int f    = fr - b * NFRAMES;
    const float* prow = pv + ((size_t)b * 128 + f) * 128;
    const float* tb   = tgt + b * N_SAMP;
    const float4* wcg = (const float4*)(wf + (size_t)fr * 512);

    float mv = (tid < 128) ? prow[tid] : -3.4e38f;
    rv[tid] = mv;
    __syncthreads();
    for (int s = 128; s > 0; s >>= 1) {
        if (tid < s) rv[tid] = fmaxf(rv[tid], rv[tid + s]);
        __syncthreads();
    }
    float m0 = rv[0];
    if (tid == 0) ccnt = 0;
    __syncthreads();
    float eps = 0.012f * fabsf(m0) + 1e-3f;    // covers fp16 single-product err
    if (tid < 128 && mv >= m0 - eps) {
        int k = atomicAdd(&ccnt, 1);
        if (k < 32) clist[k] = tid;
    }
    __syncthreads();
    int nc = ccnt;
    int total = (nc <= 32) ? nc : 128;         // paranoia: recheck all chunks
    float bestv = -3.4e38f; int bestt = 0x7fffffff;
    float* myg = stg + wv * (VSTRIDE * 4);

    for (int ci = wv; ci < total; ci += 4) {
        int c2 = (nc <= 32) ? clist[ci] : ci;
        int T0 = c2 * 256;
        // stage tb[T0-512 .. T0+255] as 192 float4 blocks (wave-private)
        for (int e = lane; e < 192; e += 64) {
            int A = T0 - 512 + 4 * e;          // always 4-aligned
            float4 vq = (A >= 0 && A < N_SAMP) ? *(const float4*)(tb + A)
                                               : make_float4(0.f, 0.f, 0.f, 0.f);
            *(float4*)(myg + 4 * e) = vq;
        }
        // conv: lane computes outputs t = T0 + 4*lane + k, k=0..3
        float4 acc = make_float4(0.f, 0.f, 0.f, 0.f);
        float4 lo = *(const float4*)(myg + 4 * (lane + 127));
        float4 hi = *(const float4*)(myg + 4 * (lane + 128));
        for (int g = 0; g < 127; ++g) {
            float4 nl = *(const float4*)(myg + 4 * (lane + 126 - g));
            const float4 c = wcg[g];
            FMA4(acc, lo, hi);
            hi = lo; lo = nl;
        }
        {
            const float4 c = wcg[127];
            FMA4(acc, lo, hi);
        }
        int tt = T0 + 4 * lane;
        if (acc.x > bestv || (acc.x == bestv && tt     < bestt)) { bestv = acc.x; bestt = tt;     }
        if (acc.y > bestv || (acc.y == bestv && tt + 1 < bestt)) { bestv = acc.y; bestt = tt + 1; }
        if (acc.z > bestv || (acc.z == bestv && tt + 2 < bestt)) { bestv = acc.z; bestt = tt + 2; }
        if (acc.w > bestv || (acc.w == bestv && tt + 3 < bestt)) { bestv = acc.w; bestt = tt + 3; }
    }
    rv[tid] = bestv; ri[tid] = bestt;
    __syncthreads();
    for (int s = 128; s > 0; s >>= 1) {
        if (tid < s) {
            float v2 = rv[tid + s]; int i2 = ri[tid + s];
            if (v2 > rv[tid] || (v2 == rv[tid] && i2 < ri[tid])) {
                rv[tid] = v2; ri[tid] = i2;
            }
        }
        __syncthreads();
    }
    if (tid == 0) marr[fr] = ri[0];
}

// ---------------------------------------------------------------- kernel H
// Precompute truncated sinc h[bf][3104] (blocks 0..507) — bit-identical op
// sequence to the original in-entry path. Block 508 = fused scheduler
// (R21: was k_sched; saves a launch) + zeroes out[0].
__global__ __launch_bounds__(256) void k_coef(const int* __restrict__ marr,
                                              float* __restrict__ hbuf,
                                              int* __restrict__ list,
                                              int* __restrict__ cnt,
                                              int nslab,
                                              float* __restrict__ out) {
    const int tid = threadIdx.x;

    if (blockIdx.x == NB * NFRAMES) {          // ---- scheduler block ----
        __shared__ int scnt[64];               // (b, region) counters
        __shared__ int total;
        if (tid == 0) out[0] = 0.0f;
        if (tid < 64) scnt[tid] = 0;
        if (tid == 0) total = 0;
        __syncthreads();
        const int RT8 = RTRUNC + 8;
        for (int bf = tid; bf < NB * NFRAMES; bf += 256) {
            int b = bf / NFRAMES;
            int m = marr[bf];
            int p = (int)rint((double)m * (32768.0 / 32769.0));
            int lo = p - RT8;        if (lo < 0) lo = 0;
            int hi = p + RT8 + 511;  if (hi > N_SAMP - 1) hi = N_SAMP - 1;
            int r0 = lo >> 11, r1 = hi >> 11;
            for (int r = r0; r <= r1; ++r) {
                int bc = (b << 4) | r;
                int s = atomicAdd(&scnt[bc], 1);
                int k = atomicAdd(&total, 1);
                list[k] = (bf << 16) | (r << 8) | s;
            }
        }
        __syncthreads();
        int n = total;
        for (int k = tid; k < n; k += 256) {   // whole-region atomic fallback
            int v = list[k];
            int bf = (v >> 16) & 0x3fff;
            int r = (v >> 8) & 15;
            int b = bf / NFRAMES;
            if (scnt[(b << 4) | r] > nslab) list[k] = v | (1 << 30);
        }
        if (tid == 0) {
            int mx = 0;
            for (int i = 0; i < 64; ++i) mx = (scnt[i] > mx) ? scnt[i] : mx;
            cnt[0] = n;
            cnt[1] = (mx > nslab) ? nslab : mx;
        }
        return;
    }

    // ---- coefficient block ----
    const int bf  = blockIdx.x;
    const double invD = 1.0 / 2147549184.0;      // 1/(65536*32769)
    const float  sd   = 4.7936899603827e-05f;    // sin(pi/65536)
    const float  trf  = (float)(RTRUNC + 4) / 65536.0f;
    int m = marr[bf];
    int p = (int)rint((double)m * (32768.0 / 32769.0));
    int jlo = p - (RTRUNC + 8); if (jlo < -512) jlo = -512; jlo &= ~3;
    float* hr = hbuf + (size_t)bf * HW;
    if (m == 0) {
        for (int k4 = tid; k4 < 776; k4 += 256) {
            int j0 = jlo + 4 * k4;
            float4 vq = make_float4((j0 == 0) ? 1.0f : 0.0f, 0.f, 0.f, 0.f);
            *(float4*)(hr + 4 * k4) = vq;
        }
        return;
    }
    double md32768 = (double)m * 32768.0;
    double sp = sin((double)m * (M_PI / 32769.0));
    float Cp = (float)(sp * (1.0 / 65536.0));
    if (m & 1) Cp = -Cp;
    float Cn = -Cp;
    for (int k4 = tid; k4 < 776; k4 += 256) {
        int j0 = jlo + 4 * k4;
        double A0 = (double)j0 * 32769.0 - md32768;
        double rA0 = A0 * invD;
        float f0v = (float)(rA0 - rint(rA0));
        float4 vq;
        if (fabsf(f0v) > trf) {
            vq = make_float4(0.f, 0.f, 0.f, 0.f);
        } else if (fabsf(f0v) < 6.2e-5f) {
#pragma unroll
            for (int k = 0; k < 4; ++k) {
                double rA = (A0 + (double)k * 32769.0) * invD;
                float ff = (float)(rA - rint(rA));
                float r2;
                if (ff == 0.0f) r2 = 65535.0f;
                else {
                    float s, c2;
                    __sincosf((float)M_PI * ff, &s, &c2);
                    r2 = c2 * __builtin_amdgcn_rcpf(s);
                }
                ((float*)&vq)[k] = ((k & 1) ? Cn : Cp) * r2;
            }
        } else {
            float s, c2;
            __sincosf((float)M_PI * f0v, &s, &c2);
            vq.x = Cp * (c2 * __builtin_amdgcn_rcpf(s));
            float s1 = fmaf(c2, sd, s);
            float c1 = fmaf(-s, sd, c2);
            vq.y = Cn * (c1 * __builtin_amdgcn_rcpf(s1));
            float s2 = fmaf(c1, sd, s1);
            float cc2 = fmaf(-s1, sd, c1);
            vq.z = Cp * (cc2 * __builtin_amdgcn_rcpf(s2));
            float s3 = fmaf(cc2, sd, s2);
            float c3 = fmaf(-s2, sd, cc2);
            vq.w = Cn * (c3 * __builtin_amdgcn_rcpf(s3));
        }
        *(float4*)(hr + 4 * k4) = vq;
    }
}

// ---------------------------------------------------------------- kernel D
// R21 conv: period-5 rolling window. ds_read for a group issued ~3 groups
// (~200cy) before first use; wc coefficients pipelined 5 groups ahead in
// SGPRs. Same group order + FMA sequence as CB3 form -> bit-identical
// (lead-in groups multiply exact-0.0f h blocks). LDS padded 8 blocks low
// so tail prefetches stay in-bounds (values never used).
#define LDB5(nn) (*(const float4*)(s_h + 4 * SW((nn) + 8)))
#define CB5(K, LOs, MIDs, HIs)                                    \
    if (gb + (K) <= gmax) {                                       \
        float4 tnew = LDB5(Lt + 124 - gb - (K));                  \
        const float4 c = c##K;                                    \
        FMA4(acc0, LOs, MIDs); FMA4(acc1, MIDs, HIs);             \
        HIs = tnew;                                               \
        c##K = wc[(gb + (K) + 5 <= 127) ? (gb + (K) + 5) : 127];  \
    }

__global__ __launch_bounds__(256, 8) void k_shift_acc(const float* __restrict__ wf,
                                                      const int* __restrict__ marr,
                                                      const int* __restrict__ list,
                                                      const int* __restrict__ cnt,
                                                      const float* __restrict__ hbuf,
                                                      float* __restrict__ part,
                                                      int slabmask) {
    __shared__ __align__(16) float s_h[2624];    // 10496 B: 8 blk/CU
    const int tid = threadIdx.x;
    const int Lt  = 2 * tid;
    const int Ltw = (tid >> 6) * 128;            // wave-uniform base block
    const int n   = cnt[0];

    for (int se = blockIdx.x; se < n; se += gridDim.x) {
        int v     = list[se];
        int bf    = (v >> 16) & 0x3fff;
        int r     = (v >> 8) & 15;
        int slot  = v & 255;
        int isat  = (v >> 30) & 1;
        int b     = bf / NFRAMES;
        int t0s   = r << 11;                     // this entry's 2048 outputs
        const float4* __restrict__ wc = (const float4*)(wf + bf * 512);

        int m  = marr[bf];
        int pr = (int)rint((double)m * (32768.0 / 32769.0));
        int jlo = pr - (RTRUNC + 8); if (jlo < -512) jlo = -512; jlo &= ~3;
        int kb0 = ((t0s - 512) - jlo) >> 2;      // both multiples of 4
        const float4* __restrict__ hb = (const float4*)(hbuf + (size_t)bf * HW);

        __syncthreads();                          // prior entry's LDS reads done
        for (int e4 = tid; e4 < 640; e4 += 256) {
            int kb = kb0 + e4;
            float4 vq = (kb >= 0 && kb < 776) ? hb[kb]
                                              : make_float4(0.f, 0.f, 0.f, 0.f);
            *(float4*)(s_h + 4 * SW(e4 + 8)) = vq;
        }
        __syncthreads();

        // nonzero coeff block range [blo,bhi] (blocks of 4 floats in s_h)
        int blo = (pr - (RTRUNC + 8) - (t0s - 512)) >> 2;
        int bhi = (pr + (RTRUNC + 8) - (t0s - 512)) >> 2;
        if (blo < 0) blo = 0;
        if (bhi > 639) bhi = 639;

        float4 acc0 = make_float4(0.f, 0.f, 0.f, 0.f);
        float4 acc1 = acc0;

        // group g uses coeff blocks {Lt+127-g .. Lt+129-g}; wave covers
        // Lt in [Ltw, Ltw+126] -> active groups [gmin, gmax]
        int gmin = Ltw + 127 - bhi; if (gmin < 0) gmin = 0;
        int gmax = Ltw + 255 - blo; if (gmax > 127) gmax = 127;
        if (gmin <= gmax) {
            int gb0 = (gmin / 5) * 5;                    // <= 125
            float4 w0 = LDB5(Lt + 129 - gb0);
            float4 w1 = LDB5(Lt + 128 - gb0);
            float4 w2 = LDB5(Lt + 127 - gb0);
            float4 w3 = LDB5(Lt + 126 - gb0);
            float4 w4 = LDB5(Lt + 125 - gb0);
            float4 c0 = wc[gb0];
            float4 c1 = wc[(gb0 + 1 <= 127) ? gb0 + 1 : 127];
            float4 c2 = wc[(gb0 + 2 <= 127) ? gb0 + 2 : 127];
            float4 c3 = wc[(gb0 + 3 <= 127) ? gb0 + 3 : 127];
            float4 c4 = wc[(gb0 + 4 <= 127) ? gb0 + 4 : 127];
            for (int gb = gb0; gb <= gmax; gb += 5) {
                CB5(0, w2, w1, w0);
                CB5(1, w3, w2, w1);
                CB5(2, w4, w3, w2);
                CB5(3, w0, w4, w3);
                CB5(4, w1, w0, w4);
            }
        }

        int slab = slot & slabmask;
        float* ob = part + (size_t)slab * (NB * N_SAMP) + b * N_SAMP + t0s;
        if (!isat) {
            *(float4*)(ob + 8 * tid)     = acc0;
            *(float4*)(ob + 8 * tid + 4) = acc1;
        } else {
            float* p0 = ob + 8 * tid;
            atomicAdd(p0 + 0, acc0.x); atomicAdd(p0 + 1, acc0.y);
            atomicAdd(p0 + 2, acc0.z); atomicAdd(p0 + 3, acc0.w);
            atomicAdd(p0 + 4, acc1.x); atomicAdd(p0 + 5, acc1.y);
            atomicAdd(p0 + 6, acc1.z); atomicAdd(p0 + 7, acc1.w);
        }
    }
}

// ---------------------------------------------------------------- kernel E
__global__ __launch_bounds__(256) void k_mse(const float* __restrict__ part,
                                             const float* __restrict__ tgt,
                                             float* __restrict__ out,
                                             const int* __restrict__ cnt,
                                             int nslab) {
    __shared__ float sred[4];
    int e = blockIdx.x * 256 + threadIdx.x;
    int ng = cnt[1];
    if (ng > nslab) ng = nslab;
    float s0 = 0.f, s1 = 0.f, s2 = 0.f, s3 = 0.f;
    int g = 0;
    for (; g + 4 <= ng; g += 4) {
        s0 += part[(size_t)(g + 0) * (NB * N_SAMP) + e];
        s1 += part[(size_t)(g + 1) * (NB * N_SAMP) + e];
        s2 += part[(size_t)(g + 2) * (NB * N_SAMP) + e];
        s3 += part[(size_t)(g + 3) * (NB * N_SAMP) + e];
    }
    for (; g < ng; ++g)
        s0 += part[(size_t)g * (NB * N_SAMP) + e];
    float s = (s0 + s1) + (s2 + s3);
    float d = s - tgt[e];
    float v = d * d;
#pragma unroll
    for (int off = 32; off > 0; off >>= 1) v += __shfl_down(v, off, 64);
    int lane = threadIdx.x & 63, wid = threadIdx.x >> 6;
    if (lane == 0) sred[wid] = v;
    __syncthreads();
    if (threadIdx.x == 0) {
        float sm = sred[0] + sred[1] + sred[2] + sred[3];
        atomicAdd(out, sm * (1.0f / 131072.0f));
    }
}

// ---------------------------------------------------------------- launch
extern "C" void kernel_launch(void* const* d_in, const int* in_sizes, int n_in,
                              void* d_out, int out_size, void* d_ws, size_t ws_size,
                              hipStream_t stream) {
    const float* recon = (const float*)d_in[0];
    const float* tgt   = (const float*)d_in[1];
    float* out = (float*)d_out;
    float* W   = (float*)d_ws;

    float*     wf   = W + WS_WF;
    _Float16*  wfh  = (_Float16*)(W + WS_WFH);
    float*     pv   = W + WS_PV;
    int*       marr = (int*)(W + WS_M);
    int*       cnt  = (int*)(W + WS_CNT);
    int*       list = (int*)(W + WS_LIST);
    float*     hbuf = W + WS_H;
    float*     part = W + WS_PART;

    int nslab = NSLAB;
    while (nslab > 1 &&
           ((size_t)WS_PART + (size_t)nslab * NB * N_SAMP) * sizeof(float) > ws_size)
        nslab >>= 1;

    hipMemsetAsync(part, 0, (size_t)nslab * NB * N_SAMP * sizeof(float), stream);

    k_wf<<<1024, 256, 0, stream>>>(recon, wf, wfh);
    k_argmax_mfma<<<1024, 256, 0, stream>>>(tgt, wfh, pv);
    k_vmax<<<NB * NFRAMES, 256, 0, stream>>>(tgt, wf, pv, marr);
    k_coef<<<NB * NFRAMES + 1, 256, 0, stream>>>(marr, hbuf, list, cnt, nslab, out);
    k_shift_acc<<<2048, 256, 0, stream>>>(wf, marr, list, cnt, hbuf, part, nslab - 1);
    k_mse<<<512, 256, 0, stream>>>(part, tgt, out, cnt, nslab);
}

// Round 8
// 157.180 us; speedup vs baseline: 1.1312x; 1.1312x over previous
//
#include <hip/hip_runtime.h>
#include <math.h>

#define N_SAMP   32768
#define WINDOW   512
#define STEP     256
#define NFRAMES  127      // (32768-512)/256 + 1
#define NB       4
#define RTRUNC   1280     // h truncation radius (samples)
#define NSLAB    32       // R16 best-measured config
#define BPAD     776      // B-copy stride (elems): 388 words = 4 mod 32 banks
#define HW       3104     // per-frame h window (floats), 776 float4 blocks
#define VSTRIDE  193      // k_vmax per-wave region stride (blocks)

// ws layout (float granularity)
#define WS_WF   0               // 4*127*512 = 260096 floats (fp32, shift conv)
#define WS_WFH  260096          // 4*64*128*8 fp16 = 131072 float slots (k-major)
#define WS_WFL  391168          // 131072 (reserved: absorbs A prefetch overrun)
#define WS_PV   522240          // 4*128*128 = 65536 (per-chunk fp16 max)
#define WS_M    587776          // 512 ints (argmax per (b,f))
#define WS_CNT  588288          // 16 ints
#define WS_LIST 588304          // 4096 ints (entry list)
#define WS_H    592400          // 508*3104 = 1576832 floats (truncated sinc)
#define WS_PART 2169232         // nslab*4*32768 floats (per-slot partials)

typedef _Float16 f16x8 __attribute__((ext_vector_type(8)));
typedef float f32x16 __attribute__((ext_vector_type(16)));

// XOR swizzle on float4-block index (conflict-free sliding reads)
#define SW(L) ((L) ^ (((L) >> 3) & 7))

#define FMA4(A, LO, HI)                                           \
    A.x = fmaf(c.x, HI.x, A.x); A.x = fmaf(c.y, LO.w, A.x);       \
    A.x = fmaf(c.z, LO.z, A.x); A.x = fmaf(c.w, LO.y, A.x);       \
    A.y = fmaf(c.x, HI.y, A.y); A.y = fmaf(c.y, HI.x, A.y);       \
    A.y = fmaf(c.z, LO.w, A.y); A.y = fmaf(c.w, LO.z, A.y);       \
    A.z = fmaf(c.x, HI.z, A.z); A.z = fmaf(c.y, HI.y, A.z);       \
    A.z = fmaf(c.z, HI.x, A.z); A.z = fmaf(c.w, LO.w, A.z);       \
    A.w = fmaf(c.x, HI.w, A.w); A.w = fmaf(c.y, HI.z, A.w);       \
    A.w = fmaf(c.z, HI.y, A.w); A.w = fmaf(c.w, HI.x, A.w);

// ---------------------------------------------------------------- kernel A
// + R22: folds the part-buffer zeroing (was a separate hipMemsetAsync).
__global__ __launch_bounds__(256) void k_wf(const float* __restrict__ recon,
                                            float* __restrict__ wf,
                                            _Float16* __restrict__ wfh,
                                            float* __restrict__ part,
                                            int nslab) {
    int e = blockIdx.x * 256 + threadIdx.x;    // 4*128*512 exactly
    int w     = e & 511;
    int bf128 = e >> 9;
    int f = bf128 & 127;
    int b = bf128 >> 7;
    float val = 0.f;
    if (f < NFRAMES) {
        float ham = 0.54f - 0.46f * (float)cos((double)w * (M_PI / 256.0));
        val = ham * recon[b * N_SAMP + f * STEP + w];
        wf[(b * NFRAMES + f) * 512 + w] = val;
    }
    size_t tr = (((size_t)b * 64 + (w >> 3)) * 128 + f) * 8 + (w & 7);
    wfh[tr] = (_Float16)val;
    // zero part: nslab*32768 float4s over 262144 threads
    float4* p4 = (float4*)part;
    int nq = nslab * 32768;
    for (int q = e; q < nq; q += 262144)
        p4[q] = make_float4(0.f, 0.f, 0.f, 0.f);
}

// ---------------------------------------------------------------- kernel B
// fm = wf x Toeplitz(tgt), fp16 32x32x16 MFMA; two M-tiles per wave.
// R22: Toeplitz staging via coalesced float4 -> LDS float buffer -> reversed
// f16x8 rows (was 6144 scalar descending global loads/block). Same f32->f16
// conversion of the same values -> bit-exact.
__global__ __launch_bounds__(256, 4) void k_argmax_mfma(
        const float* __restrict__ tgt,
        const _Float16* __restrict__ wfh,
        float* __restrict__ pv) {
    __shared__ _Float16 sbh[8 * BPAD];         // 12416 B
    __shared__ __align__(16) float stf[768];   // 3072 B
    const int tid   = threadIdx.x;
    const int chunk = blockIdx.x & 127;        // 256-t chunk
    const int half  = (blockIdx.x >> 7) & 1;   // 64-frame group
    const int b     = blockIdx.x >> 8;
    const int T0    = chunk * 256;
    const int TB    = T0 + 255;
    const float* tb = tgt + b * N_SAMP;

    if (tid < 192) {                           // tb[TB-767 .. TB], 4-aligned
        int A = TB - 767 + 4 * tid;
        float4 vq = (A >= 0) ? *(const float4*)(tb + A)
                             : make_float4(0.f, 0.f, 0.f, 0.f);
        *(float4*)(stf + 4 * tid) = vq;
    }
    __syncthreads();
    for (int oc = tid; oc < 768; oc += 256) {
        int r = oc / 96, s = oc - r * 96;
        int y0 = 767 - r - 8 * s;              // y index for j=0
        _Float16 h8[8];
#pragma unroll
        for (int j = 0; j < 8; ++j)
            h8[j] = (_Float16)stf[y0 - j];
        *(f16x8*)&sbh[r * BPAD + 8 * s] = *(f16x8*)h8;
    }
    __syncthreads();

    const int wv  = tid >> 6;
    const int q   = (tid >> 5) & 1;
    const int cl  = tid & 31;
    const int nt0 = 2 * wv;
    const int rp  = 7 - (cl & 7);
    const _Float16* Ah0 = wfh + ((size_t)b * 64) * 1024 + (half * 64 + cl) * 8;

    f32x16 acc00 = (f32x16)(0.f);
    f32x16 acc01 = (f32x16)(0.f);
    f32x16 acc10 = (f32x16)(0.f);
    f32x16 acc11 = (f32x16)(0.f);

    int off = q * 1024;                        // k-slice q; +2048/iter
    int ea  = rp * BPAD + (255 - 32 * nt0 - cl + 8 * q - rp);
    f16x8 a0  = *(const f16x8*)(Ah0 + off);
    f16x8 a1  = *(const f16x8*)(Ah0 + off + 256);
    f16x8 bh0 = *(const f16x8*)&sbh[ea];
    f16x8 bh1 = *(const f16x8*)&sbh[ea - 32];
#pragma unroll
    for (int k0 = 0; k0 < 512; k0 += 16) {
        f16x8 a0n  = *(const f16x8*)(Ah0 + off + 2048);   // overrun -> wfl slot
        f16x8 a1n  = *(const f16x8*)(Ah0 + off + 2304);
        f16x8 bh0n = *(const f16x8*)&sbh[ea + 16];
        f16x8 bh1n = *(const f16x8*)&sbh[ea - 16];
        acc00 = __builtin_amdgcn_mfma_f32_32x32x16_f16(a0, bh0, acc00, 0, 0, 0);
        acc01 = __builtin_amdgcn_mfma_f32_32x32x16_f16(a0, bh1, acc01, 0, 0, 0);
        acc10 = __builtin_amdgcn_mfma_f32_32x32x16_f16(a1, bh0, acc10, 0, 0, 0);
        acc11 = __builtin_amdgcn_mfma_f32_32x32x16_f16(a1, bh1, acc11, 0, 0, 0);
        a0 = a0n; a1 = a1n; bh0 = bh0n; bh1 = bh1n;
        off += 2048; ea += 16;
    }

    __syncthreads();
    float* sval = (float*)sbh;                 // 64 rows x 4 waves
#pragma unroll
    for (int r = 0; r < 16; ++r) {
        float v0 = fmaxf(acc00[r], acc01[r]);
        float v1 = fmaxf(acc10[r], acc11[r]);
#pragma unroll
        for (int mm = 1; mm <= 16; mm <<= 1) {
            v0 = fmaxf(v0, __shfl_xor(v0, mm));
            v1 = fmaxf(v1, __shfl_xor(v1, mm));
        }
        if (cl == 0) {
            int row = (r & 3) + 8 * (r >> 2) + 4 * q;
            sval[row * 4 + wv]        = v0;
            sval[(32 + row) * 4 + wv] = v1;
        }
    }
    __syncthreads();
    if (tid < 64) {
        float v = fmaxf(fmaxf(sval[tid * 4], sval[tid * 4 + 1]),
                        fmaxf(sval[tid * 4 + 2], sval[tid * 4 + 3]));
        pv[((size_t)b * 128 + half * 64 + tid) * 128 + chunk] = v;
    }
}

// ---------------------------------------------------------------- kernel C
// R20 form: one wave per candidate, FMA4 sliding-block conv, bit-identical
// accumulation order (w2 ascending).
__global__ __launch_bounds__(256) void k_vmax(const float* __restrict__ tgt,
                                              const float* __restrict__ wf,
                                              const float* __restrict__ pv,
                                              int* __restrict__ marr) {
    __shared__ __align__(16) float stg[4 * VSTRIDE * 4];  // 12352 B
    __shared__ float rv[256];
    __shared__ int   ri[256];
    __shared__ int   clist[32];
    __shared__ int   ccnt;
    const int tid  = threadIdx.x;
    const int lane = tid & 63;
    const int wv   = tid >> 6;
    const int fr   = blockIdx.x;
    const int b    = fr / NFRAMES;
    const int f    = fr - b * NFRAMES;
    const float* prow = pv + ((size_t)b * 128 + f) * 128;
    const float* tb   = tgt + b * N_SAMP;
    const float4* wcg = (const float4*)(wf + (size_t)fr * 512);

    float mv = (tid < 128) ? prow[tid] : -3.4e38f;
    rv[tid] = mv;
    __syncthreads();
    for (int s = 128; s > 0; s >>= 1) {
        if (tid < s) rv[tid] = fmaxf(rv[tid], rv[tid + s]);
        __syncthreads();
    }
    float m0 = rv[0];
    if (tid == 0) ccnt = 0;
    __syncthreads();
    float eps = 0.012f * fabsf(m0) + 1e-3f;    // covers fp16 single-product err
    if (tid < 128 && mv >= m0 - eps) {
        int k = atomicAdd(&ccnt, 1);
        if (k < 32) clist[k] = tid;
    }
    __syncthreads();
    int nc = ccnt;
    int total = (nc <= 32) ? nc : 128;         // paranoia: recheck all chunks
    float bestv = -3.4e38f; int bestt = 0x7fffffff;
    float* myg = stg + wv * (VSTRIDE * 4);

    for (int ci = wv; ci < total; ci += 4) {
        int c2 = (nc <= 32) ? clist[ci] : ci;
        int T0 = c2 * 256;
        // stage tb[T0-512 .. T0+255] as 192 float4 blocks (wave-private)
        for (int e = lane; e < 192; e += 64) {
            int A = T0 - 512 + 4 * e;          // always 4-aligned
            float4 vq = (A >= 0 && A < N_SAMP) ? *(const float4*)(tb + A)
                                               : make_float4(0.f, 0.f, 0.f, 0.f);
            *(float4*)(myg + 4 * e) = vq;
        }
        // conv: lane computes outputs t = T0 + 4*lane + k, k=0..3
        float4 acc = make_float4(0.f, 0.f, 0.f, 0.f);
        float4 lo = *(const float4*)(myg + 4 * (lane + 127));
        float4 hi = *(const float4*)(myg + 4 * (lane + 128));
        for (int g = 0; g < 127; ++g) {
            float4 nl = *(const float4*)(myg + 4 * (lane + 126 - g));
            const float4 c = wcg[g];
            FMA4(acc, lo, hi);
            hi = lo; lo = nl;
        }
        {
            const float4 c = wcg[127];
            FMA4(acc, lo, hi);
        }
        int tt = T0 + 4 * lane;
        if (acc.x > bestv || (acc.x == bestv && tt     < bestt)) { bestv = acc.x; bestt = tt;     }
        if (acc.y > bestv || (acc.y == bestv && tt + 1 < bestt)) { bestv = acc.y; bestt = tt + 1; }
        if (acc.z > bestv || (acc.z == bestv && tt + 2 < bestt)) { bestv = acc.z; bestt = tt + 2; }
        if (acc.w > bestv || (acc.w == bestv && tt + 3 < bestt)) { bestv = acc.w; bestt = tt + 3; }
    }
    rv[tid] = bestv; ri[tid] = bestt;
    __syncthreads();
    for (int s = 128; s > 0; s >>= 1) {
        if (tid < s) {
            float v2 = rv[tid + s]; int i2 = ri[tid + s];
            if (v2 > rv[tid] || (v2 == rv[tid] && i2 < ri[tid])) {
                rv[tid] = v2; ri[tid] = i2;
            }
        }
        __syncthreads();
    }
    if (tid == 0) marr[fr] = ri[0];
}

// ---------------------------------------------------------------- kernel H
// Precompute truncated sinc h[bf][3104] (blocks 0..507) — bit-identical op
// sequence to the original in-entry path. Block 508 = fused scheduler
// (saves a launch) + zeroes out[0].
__global__ __launch_bounds__(256) void k_coef(const int* __restrict__ marr,
                                              float* __restrict__ hbuf,
                                              int* __restrict__ list,
                                              int* __restrict__ cnt,
                                              int nslab,
                                              float* __restrict__ out) {
    const int tid = threadIdx.x;

    if (blockIdx.x == NB * NFRAMES) {          // ---- scheduler block ----
        __shared__ int scnt[64];               // (b, region) counters
        __shared__ int total;
        if (tid == 0) out[0] = 0.0f;
        if (tid < 64) scnt[tid] = 0;
        if (tid == 0) total = 0;
        __syncthreads();
        const int RT8 = RTRUNC + 8;
        for (int bf = tid; bf < NB * NFRAMES; bf += 256) {
            int b = bf / NFRAMES;
            int m = marr[bf];
            int p = (int)rint((double)m * (32768.0 / 32769.0));
            int lo = p - RT8;        if (lo < 0) lo = 0;
            int hi = p + RT8 + 511;  if (hi > N_SAMP - 1) hi = N_SAMP - 1;
            int r0 = lo >> 11, r1 = hi >> 11;
            for (int r = r0; r <= r1; ++r) {
                int bc = (b << 4) | r;
                int s = atomicAdd(&scnt[bc], 1);
                int k = atomicAdd(&total, 1);
                list[k] = (bf << 16) | (r << 8) | s;
            }
        }
        __syncthreads();
        int n = total;
        for (int k = tid; k < n; k += 256) {   // whole-region atomic fallback
            int v = list[k];
            int bf = (v >> 16) & 0x3fff;
            int r = (v >> 8) & 15;
            int b = bf / NFRAMES;
            if (scnt[(b << 4) | r] > nslab) list[k] = v | (1 << 30);
        }
        if (tid == 0) {
            int mx = 0;
            for (int i = 0; i < 64; ++i) mx = (scnt[i] > mx) ? scnt[i] : mx;
            cnt[0] = n;
            cnt[1] = (mx > nslab) ? nslab : mx;
        }
        return;
    }

    // ---- coefficient block ----
    const int bf  = blockIdx.x;
    const double invD = 1.0 / 2147549184.0;      // 1/(65536*32769)
    const float  sd   = 4.7936899603827e-05f;    // sin(pi/65536)
    const float  trf  = (float)(RTRUNC + 4) / 65536.0f;
    int m = marr[bf];
    int p = (int)rint((double)m * (32768.0 / 32769.0));
    int jlo = p - (RTRUNC + 8); if (jlo < -512) jlo = -512; jlo &= ~3;
    float* hr = hbuf + (size_t)bf * HW;
    if (m == 0) {
        for (int k4 = tid; k4 < 776; k4 += 256) {
            int j0 = jlo + 4 * k4;
            float4 vq = make_float4((j0 == 0) ? 1.0f : 0.0f, 0.f, 0.f, 0.f);
            *(float4*)(hr + 4 * k4) = vq;
        }
        return;
    }
    double md32768 = (double)m * 32768.0;
    double sp = sin((double)m * (M_PI / 32769.0));
    float Cp = (float)(sp * (1.0 / 65536.0));
    if (m & 1) Cp = -Cp;
    float Cn = -Cp;
    for (int k4 = tid; k4 < 776; k4 += 256) {
        int j0 = jlo + 4 * k4;
        double A0 = (double)j0 * 32769.0 - md32768;
        double rA0 = A0 * invD;
        float f0v = (float)(rA0 - rint(rA0));
        float4 vq;
        if (fabsf(f0v) > trf) {
            vq = make_float4(0.f, 0.f, 0.f, 0.f);
        } else if (fabsf(f0v) < 6.2e-5f) {
#pragma unroll
            for (int k = 0; k < 4; ++k) {
                double rA = (A0 + (double)k * 32769.0) * invD;
                float ff = (float)(rA - rint(rA));
                float r2;
                if (ff == 0.0f) r2 = 65535.0f;
                else {
                    float s, c2;
                    __sincosf((float)M_PI * ff, &s, &c2);
                    r2 = c2 * __builtin_amdgcn_rcpf(s);
                }
                ((float*)&vq)[k] = ((k & 1) ? Cn : Cp) * r2;
            }
        } else {
            float s, c2;
            __sincosf((float)M_PI * f0v, &s, &c2);
            vq.x = Cp * (c2 * __builtin_amdgcn_rcpf(s));
            float s1 = fmaf(c2, sd, s);
            float c1 = fmaf(-s, sd, c2);
            vq.y = Cn * (c1 * __builtin_amdgcn_rcpf(s1));
            float s2 = fmaf(c1, sd, s1);
            float cc2 = fmaf(-s1, sd, c1);
            vq.z = Cp * (cc2 * __builtin_amdgcn_rcpf(s2));
            float s3 = fmaf(cc2, sd, s2);
            float c3 = fmaf(-s2, sd, cc2);
            vq.w = Cn * (c3 * __builtin_amdgcn_rcpf(s3));
        }
        *(float4*)(hr + 4 * k4) = vq;
    }
}

// ---------------------------------------------------------------- kernel D
// One 2048-output region per list entry (R3 CB3 form — best measured,
// 42.9us; R4/R6 schedule variants both regressed — do not touch).
#define LDBLK2(nn) (*(const float4*)(s_h + 4 * SW(Lt + (nn))))
#define CB3(g, A, Bq, Cq)                                         \
    {                                                             \
        float4 tnew = LDBLK2(126 - (g));                          \
        const float4 c = wc[(g)];                                 \
        FMA4(acc0, w[A], w[Bq]); FMA4(acc1, w[Bq], w[Cq]);        \
        w[Cq] = tnew;                                             \
    }
#define CB3_NL(g, A, Bq, Cq)                                      \
    {                                                             \
        const float4 c = wc[(g)];                                 \
        FMA4(acc0, w[A], w[Bq]); FMA4(acc1, w[Bq], w[Cq]);        \
    }

__global__ __launch_bounds__(256, 8) void k_shift_acc(const float* __restrict__ wf,
                                                      const int* __restrict__ marr,
                                                      const int* __restrict__ list,
                                                      const int* __restrict__ cnt,
                                                      const float* __restrict__ hbuf,
                                                      float* __restrict__ part,
                                                      int slabmask) {
    __shared__ __align__(16) float s_h[2560];    // 10240 B: 8 blk/CU
    const int tid = threadIdx.x;
    const int Lt  = 2 * tid;
    const int Ltw = (tid >> 6) * 128;            // wave-uniform base block
    const int n   = cnt[0];

    for (int se = blockIdx.x; se < n; se += gridDim.x) {
        int v     = list[se];
        int bf    = (v >> 16) & 0x3fff;
        int r     = (v >> 8) & 15;
        int slot  = v & 255;
        int isat  = (v >> 30) & 1;
        int b     = bf / NFRAMES;
        int t0s   = r << 11;                     // this entry's 2048 outputs
        const float4* __restrict__ wc = (const float4*)(wf + bf * 512);

        int m  = marr[bf];
        int pr = (int)rint((double)m * (32768.0 / 32769.0));
        int jlo = pr - (RTRUNC + 8); if (jlo < -512) jlo = -512; jlo &= ~3;
        int kb0 = ((t0s - 512) - jlo) >> 2;      // both multiples of 4
        const float4* __restrict__ hb = (const float4*)(hbuf + (size_t)bf * HW);

        __syncthreads();                          // prior entry's LDS reads done
        for (int e4 = tid; e4 < 640; e4 += 256) {
            int kb = kb0 + e4;
            float4 vq = (kb >= 0 && kb < 776) ? hb[kb]
                                              : make_float4(0.f, 0.f, 0.f, 0.f);
            *(float4*)(s_h + 4 * SW(e4)) = vq;
        }
        __syncthreads();

        // nonzero coeff block range [blo,bhi] (blocks of 4 floats in s_h)
        int blo = (pr - (RTRUNC + 8) - (t0s - 512)) >> 2;
        int bhi = (pr + (RTRUNC + 8) - (t0s - 512)) >> 2;
        if (blo < 0) blo = 0;
        if (bhi > 639) bhi = 639;

        float4 acc0 = make_float4(0.f, 0.f, 0.f, 0.f);
        float4 acc1 = acc0;

        // group g uses coeff blocks {Lt+127-g .. Lt+129-g}; wave covers
        // Lt in [Ltw, Ltw+126] -> active groups [gmin, gmax]
        int gmin = Ltw + 127 - bhi; if (gmin < 0) gmin = 0;
        int gmax = Ltw + 255 - blo; if (gmax > 127) gmax = 127;
        if (gmin <= gmax) {
            int go0 = gmin / 3;                          // <= 42
            bool tail = (gmax >= 126);
            int goE = tail ? 42 : (gmax / 3 + 1);        // exclusive, <= 42
            int gb0 = 3 * go0;
            float4 w[3];
            w[0] = LDBLK2(127 - gb0);
            w[1] = LDBLK2(128 - gb0);
            w[2] = LDBLK2(129 - gb0);
            for (int go = go0; go < goE && go < 42; ++go) {
                const int gb = 3 * go;
                CB3(gb + 0, 0, 1, 2);
                CB3(gb + 1, 2, 0, 1);
                CB3(gb + 2, 1, 2, 0);
            }
            if (tail) { CB3(126, 0, 1, 2); CB3_NL(127, 2, 0, 1); }
        }

        int slab = slot & slabmask;
        float* ob = part + (size_t)slab * (NB * N_SAMP) + b * N_SAMP + t0s;
        if (!isat) {
            *(float4*)(ob + 8 * tid)     = acc0;
            *(float4*)(ob + 8 * tid + 4) = acc1;
        } else {
            float* p0 = ob + 8 * tid;
            atomicAdd(p0 + 0, acc0.x); atomicAdd(p0 + 1, acc0.y);
            atomicAdd(p0 + 2, acc0.z); atomicAdd(p0 + 3, acc0.w);
            atomicAdd(p0 + 4, acc1.x); atomicAdd(p0 + 5, acc1.y);
            atomicAdd(p0 + 6, acc1.z); atomicAdd(p0 + 7, acc1.w);
        }
    }
}

// ---------------------------------------------------------------- kernel E
__global__ __launch_bounds__(256) void k_mse(const float* __restrict__ part,
                                             const float* __restrict__ tgt,
                                             float* __restrict__ out,
                                             const int* __restrict__ cnt,
                                             int nslab) {
    __shared__ float sred[4];
    int e = blockIdx.x * 256 + threadIdx.x;
    int ng = cnt[1];
    if (ng > nslab) ng = nslab;
    float s0 = 0.f, s1 = 0.f, s2 = 0.f, s3 = 0.f;
    int g = 0;
    for (; g + 4 <= ng; g += 4) {
        s0 += part[(size_t)(g + 0) * (NB * N_SAMP) + e];
        s1 += part[(size_t)(g + 1) * (NB * N_SAMP) + e];
        s2 += part[(size_t)(g + 2) * (NB * N_SAMP) + e];
        s3 += part[(size_t)(g + 3) * (NB * N_SAMP) + e];
    }
    for (; g < ng; ++g)
        s0 += part[(size_t)g * (NB * N_SAMP) + e];
    float s = (s0 + s1) + (s2 + s3);
    float d = s - tgt[e];
    float v = d * d;
#pragma unroll
    for (int off = 32; off > 0; off >>= 1) v += __shfl_down(v, off, 64);
    int lane = threadIdx.x & 63, wid = threadIdx.x >> 6;
    if (lane == 0) sred[wid] = v;
    __syncthreads();
    if (threadIdx.x == 0) {
        float sm = sred[0] + sred[1] + sred[2] + sred[3];
        atomicAdd(out, sm * (1.0f / 131072.0f));
    }
}

// ---------------------------------------------------------------- launch
extern "C" void kernel_launch(void* const* d_in, const int* in_sizes, int n_in,
                              void* d_out, int out_size, void* d_ws, size_t ws_size,
                              hipStream_t stream) {
    const float* recon = (const float*)d_in[0];
    const float* tgt   = (const float*)d_in[1];
    float* out = (float*)d_out;
    float* W   = (float*)d_ws;

    float*     wf   = W + WS_WF;
    _Float16*  wfh  = (_Float16*)(W + WS_WFH);
    float*     pv   = W + WS_PV;
    int*       marr = (int*)(W + WS_M);
    int*       cnt  = (int*)(W + WS_CNT);
    int*       list = (int*)(W + WS_LIST);
    float*     hbuf = W + WS_H;
    float*     part = W + WS_PART;

    int nslab = NSLAB;
    while (nslab > 1 &&
           ((size_t)WS_PART + (size_t)nslab * NB * N_SAMP) * sizeof(float) > ws_size)
        nslab >>= 1;

    k_wf<<<1024, 256, 0, stream>>>(recon, wf, wfh, part, nslab);
    k_argmax_mfma<<<1024, 256, 0, stream>>>(tgt, wfh, pv);
    k_vmax<<<NB * NFRAMES, 256, 0, stream>>>(tgt, wf, pv, marr);
    k_coef<<<NB * NFRAMES + 1, 256, 0, stream>>>(marr, hbuf, list, cnt, nslab, out);
    k_shift_acc<<<2048, 256, 0, stream>>>(wf, marr, list, cnt, hbuf, part, nslab - 1);
    k_mse<<<512, 256, 0, stream>>>(part, tgt, out, cnt, nslab);
}

// Round 9
// 154.538 us; speedup vs baseline: 1.1505x; 1.0171x over previous
//
#include <hip/hip_runtime.h>
#include <math.h>

#define N_SAMP   32768
#define WINDOW   512
#define STEP     256
#define NFRAMES  127      // (32768-512)/256 + 1
#define NB       4
#define RTRUNC   1280     // h truncation radius (samples)
#define NSLAB    32       // R16 best-measured config
#define BPAD     776      // B-copy stride (elems): 388 words = 4 mod 32 banks
#define HW       3104     // per-frame h window (floats), 776 float4 blocks
#define VSTRIDE  193      // k_vmax per-wave region stride (blocks)

// ws layout (float granularity)
#define WS_WF   0               // 4*127*512 = 260096 floats (fp32, shift conv)
#define WS_WFH  260096          // 4*64*128*8 fp16 = 131072 float slots (k-major)
#define WS_WFL  391168          // 131072 (reserved: absorbs A prefetch overrun)
#define WS_PV   522240          // 4*128*128 = 65536 (per-chunk fp16 max)
#define WS_M    587776          // 512 ints (argmax per (b,f))
#define WS_CNT  588288          // 16 ints
#define WS_LIST 588304          // 4096 ints (entry list)
#define WS_H    592400          // 508*3104 = 1576832 floats (truncated sinc)
#define WS_PART 2169232         // nslab*4*32768 floats (per-slot partials)

typedef _Float16 f16x8 __attribute__((ext_vector_type(8)));
typedef float f32x16 __attribute__((ext_vector_type(16)));

// XOR swizzle on float4-block index (conflict-free sliding reads)
#define SW(L) ((L) ^ (((L) >> 3) & 7))

#define FMA4(A, LO, HI)                                           \
    A.x = fmaf(c.x, HI.x, A.x); A.x = fmaf(c.y, LO.w, A.x);       \
    A.x = fmaf(c.z, LO.z, A.x); A.x = fmaf(c.w, LO.y, A.x);       \
    A.y = fmaf(c.x, HI.y, A.y); A.y = fmaf(c.y, HI.x, A.y);       \
    A.y = fmaf(c.z, LO.w, A.y); A.y = fmaf(c.w, LO.z, A.y);       \
    A.z = fmaf(c.x, HI.z, A.z); A.z = fmaf(c.y, HI.y, A.z);       \
    A.z = fmaf(c.z, HI.x, A.z); A.z = fmaf(c.w, LO.w, A.z);       \
    A.w = fmaf(c.x, HI.w, A.w); A.w = fmaf(c.y, HI.z, A.w);       \
    A.w = fmaf(c.z, HI.y, A.w); A.w = fmaf(c.w, HI.x, A.w);

// ---------------------------------------------------------------- kernel A
// + folds the part-buffer zeroing (was a separate hipMemsetAsync).
__global__ __launch_bounds__(256) void k_wf(const float* __restrict__ recon,
                                            float* __restrict__ wf,
                                            _Float16* __restrict__ wfh,
                                            float* __restrict__ part,
                                            int nslab) {
    int e = blockIdx.x * 256 + threadIdx.x;    // 4*128*512 exactly
    int w     = e & 511;
    int bf128 = e >> 9;
    int f = bf128 & 127;
    int b = bf128 >> 7;
    float val = 0.f;
    if (f < NFRAMES) {
        float ham = 0.54f - 0.46f * (float)cos((double)w * (M_PI / 256.0));
        val = ham * recon[b * N_SAMP + f * STEP + w];
        wf[(b * NFRAMES + f) * 512 + w] = val;
    }
    size_t tr = (((size_t)b * 64 + (w >> 3)) * 128 + f) * 8 + (w & 7);
    wfh[tr] = (_Float16)val;
    // zero part: nslab*32768 float4s over 262144 threads
    float4* p4 = (float4*)part;
    int nq = nslab * 32768;
    for (int q = e; q < nq; q += 262144)
        p4[q] = make_float4(0.f, 0.f, 0.f, 0.f);
}

// ---------------------------------------------------------------- kernel B
// fm = wf x Toeplitz(tgt), fp16 32x32x16 MFMA; two M-tiles per wave.
// Coalesced float4->LDS staging for the Toeplitz rows (R22, bit-exact).
__global__ __launch_bounds__(256, 4) void k_argmax_mfma(
        const float* __restrict__ tgt,
        const _Float16* __restrict__ wfh,
        float* __restrict__ pv) {
    __shared__ _Float16 sbh[8 * BPAD];         // 12416 B
    __shared__ __align__(16) float stf[768];   // 3072 B
    const int tid   = threadIdx.x;
    const int chunk = blockIdx.x & 127;        // 256-t chunk
    const int half  = (blockIdx.x >> 7) & 1;   // 64-frame group
    const int b     = blockIdx.x >> 8;
    const int T0    = chunk * 256;
    const int TB    = T0 + 255;
    const float* tb = tgt + b * N_SAMP;

    if (tid < 192) {                           // tb[TB-767 .. TB], 4-aligned
        int A = TB - 767 + 4 * tid;
        float4 vq = (A >= 0) ? *(const float4*)(tb + A)
                             : make_float4(0.f, 0.f, 0.f, 0.f);
        *(float4*)(stf + 4 * tid) = vq;
    }
    __syncthreads();
    for (int oc = tid; oc < 768; oc += 256) {
        int r = oc / 96, s = oc - r * 96;
        int y0 = 767 - r - 8 * s;              // y index for j=0
        _Float16 h8[8];
#pragma unroll
        for (int j = 0; j < 8; ++j)
            h8[j] = (_Float16)stf[y0 - j];
        *(f16x8*)&sbh[r * BPAD + 8 * s] = *(f16x8*)h8;
    }
    __syncthreads();

    const int wv  = tid >> 6;
    const int q   = (tid >> 5) & 1;
    const int cl  = tid & 31;
    const int nt0 = 2 * wv;
    const int rp  = 7 - (cl & 7);
    const _Float16* Ah0 = wfh + ((size_t)b * 64) * 1024 + (half * 64 + cl) * 8;

    f32x16 acc00 = (f32x16)(0.f);
    f32x16 acc01 = (f32x16)(0.f);
    f32x16 acc10 = (f32x16)(0.f);
    f32x16 acc11 = (f32x16)(0.f);

    int off = q * 1024;                        // k-slice q; +2048/iter
    int ea  = rp * BPAD + (255 - 32 * nt0 - cl + 8 * q - rp);
    f16x8 a0  = *(const f16x8*)(Ah0 + off);
    f16x8 a1  = *(const f16x8*)(Ah0 + off + 256);
    f16x8 bh0 = *(const f16x8*)&sbh[ea];
    f16x8 bh1 = *(const f16x8*)&sbh[ea - 32];
#pragma unroll
    for (int k0 = 0; k0 < 512; k0 += 16) {
        f16x8 a0n  = *(const f16x8*)(Ah0 + off + 2048);   // overrun -> wfl slot
        f16x8 a1n  = *(const f16x8*)(Ah0 + off + 2304);
        f16x8 bh0n = *(const f16x8*)&sbh[ea + 16];
        f16x8 bh1n = *(const f16x8*)&sbh[ea - 16];
        acc00 = __builtin_amdgcn_mfma_f32_32x32x16_f16(a0, bh0, acc00, 0, 0, 0);
        acc01 = __builtin_amdgcn_mfma_f32_32x32x16_f16(a0, bh1, acc01, 0, 0, 0);
        acc10 = __builtin_amdgcn_mfma_f32_32x32x16_f16(a1, bh0, acc10, 0, 0, 0);
        acc11 = __builtin_amdgcn_mfma_f32_32x32x16_f16(a1, bh1, acc11, 0, 0, 0);
        a0 = a0n; a1 = a1n; bh0 = bh0n; bh1 = bh1n;
        off += 2048; ea += 16;
    }

    __syncthreads();
    float* sval = (float*)sbh;                 // 64 rows x 4 waves
#pragma unroll
    for (int r = 0; r < 16; ++r) {
        float v0 = fmaxf(acc00[r], acc01[r]);
        float v1 = fmaxf(acc10[r], acc11[r]);
#pragma unroll
        for (int mm = 1; mm <= 16; mm <<= 1) {
            v0 = fmaxf(v0, __shfl_xor(v0, mm));
            v1 = fmaxf(v1, __shfl_xor(v1, mm));
        }
        if (cl == 0) {
            int row = (r & 3) + 8 * (r >> 2) + 4 * q;
            sval[row * 4 + wv]        = v0;
            sval[(32 + row) * 4 + wv] = v1;
        }
    }
    __syncthreads();
    if (tid < 64) {
        float v = fmaxf(fmaxf(sval[tid * 4], sval[tid * 4 + 1]),
                        fmaxf(sval[tid * 4 + 2], sval[tid * 4 + 3]));
        pv[((size_t)b * 128 + half * 64 + tid) * 128 + chunk] = v;
    }
}

// ---------------------------------------------------------------- kernel C+H
// R23: vmax (exact candidate recheck + argmax) fused with coef (per-frame
// truncated-sinc row) — block bf needs only its OWN m for coef, so no
// grid-wide wait between the phases. Both bodies verbatim (bit-exact).
__global__ __launch_bounds__(256) void k_vmax_coef(const float* __restrict__ tgt,
                                                   const float* __restrict__ wf,
                                                   const float* __restrict__ pv,
                                                   int* __restrict__ marr,
                                                   float* __restrict__ hbuf) {
    __shared__ __align__(16) float stg[4 * VSTRIDE * 4];  // 12352 B
    __shared__ float rv[256];
    __shared__ int   ri[256];
    __shared__ int   clist[32];
    __shared__ int   ccnt;
    const int tid  = threadIdx.x;
    const int lane = tid & 63;
    const int wv   = tid >> 6;
    const int fr   = blockIdx.x;
    const int b    = fr / NFRAMES;
    const int f    = fr - b * NFRAMES;
    const float* prow = pv + ((size_t)b * 128 + f) * 128;
    const float* tb   = tgt + b * N_SAMP;
    const float4* wcg = (const float4*)(wf + (size_t)fr * 512);

    float mv = (tid < 128) ? prow[tid] : -3.4e38f;
    rv[tid] = mv;
    __syncthreads();
    for (int s = 128; s > 0; s >>= 1) {
        if (tid < s) rv[tid] = fmaxf(rv[tid], rv[tid + s]);
        __syncthreads();
    }
    float m0 = rv[0];
    if (tid == 0) ccnt = 0;
    __syncthreads();
    float eps = 0.012f * fabsf(m0) + 1e-3f;    // covers fp16 single-product err
    if (tid < 128 && mv >= m0 - eps) {
        int k = atomicAdd(&ccnt, 1);
        if (k < 32) clist[k] = tid;
    }
    __syncthreads();
    int nc = ccnt;
    int total = (nc <= 32) ? nc : 128;         // paranoia: recheck all chunks
    float bestv = -3.4e38f; int bestt = 0x7fffffff;
    float* myg = stg + wv * (VSTRIDE * 4);

    for (int ci = wv; ci < total; ci += 4) {
        int c2 = (nc <= 32) ? clist[ci] : ci;
        int T0 = c2 * 256;
        for (int e = lane; e < 192; e += 64) {
            int A = T0 - 512 + 4 * e;          // always 4-aligned
            float4 vq = (A >= 0 && A < N_SAMP) ? *(const float4*)(tb + A)
                                               : make_float4(0.f, 0.f, 0.f, 0.f);
            *(float4*)(myg + 4 * e) = vq;
        }
        float4 acc = make_float4(0.f, 0.f, 0.f, 0.f);
        float4 lo = *(const float4*)(myg + 4 * (lane + 127));
        float4 hi = *(const float4*)(myg + 4 * (lane + 128));
        for (int g = 0; g < 127; ++g) {
            float4 nl = *(const float4*)(myg + 4 * (lane + 126 - g));
            const float4 c = wcg[g];
            FMA4(acc, lo, hi);
            hi = lo; lo = nl;
        }
        {
            const float4 c = wcg[127];
            FMA4(acc, lo, hi);
        }
        int tt = T0 + 4 * lane;
        if (acc.x > bestv || (acc.x == bestv && tt     < bestt)) { bestv = acc.x; bestt = tt;     }
        if (acc.y > bestv || (acc.y == bestv && tt + 1 < bestt)) { bestv = acc.y; bestt = tt + 1; }
        if (acc.z > bestv || (acc.z == bestv && tt + 2 < bestt)) { bestv = acc.z; bestt = tt + 2; }
        if (acc.w > bestv || (acc.w == bestv && tt + 3 < bestt)) { bestv = acc.w; bestt = tt + 3; }
    }
    rv[tid] = bestv; ri[tid] = bestt;
    __syncthreads();
    for (int s = 128; s > 0; s >>= 1) {
        if (tid < s) {
            float v2 = rv[tid + s]; int i2 = ri[tid + s];
            if (v2 > rv[tid] || (v2 == rv[tid] && i2 < ri[tid])) {
                rv[tid] = v2; ri[tid] = i2;
            }
        }
        __syncthreads();
    }
    int m = ri[0];
    if (tid == 0) marr[fr] = m;

    // ---- coef phase (same block's m; bit-identical op sequence) ----
    const double invD = 1.0 / 2147549184.0;      // 1/(65536*32769)
    const float  sd   = 4.7936899603827e-05f;    // sin(pi/65536)
    const float  trf  = (float)(RTRUNC + 4) / 65536.0f;
    int p = (int)rint((double)m * (32768.0 / 32769.0));
    int jlo = p - (RTRUNC + 8); if (jlo < -512) jlo = -512; jlo &= ~3;
    float* hr = hbuf + (size_t)fr * HW;
    if (m == 0) {
        for (int k4 = tid; k4 < 776; k4 += 256) {
            int j0 = jlo + 4 * k4;
            float4 vq = make_float4((j0 == 0) ? 1.0f : 0.0f, 0.f, 0.f, 0.f);
            *(float4*)(hr + 4 * k4) = vq;
        }
        return;
    }
    double md32768 = (double)m * 32768.0;
    double sp = sin((double)m * (M_PI / 32769.0));
    float Cp = (float)(sp * (1.0 / 65536.0));
    if (m & 1) Cp = -Cp;
    float Cn = -Cp;
    for (int k4 = tid; k4 < 776; k4 += 256) {
        int j0 = jlo + 4 * k4;
        double A0 = (double)j0 * 32769.0 - md32768;
        double rA0 = A0 * invD;
        float f0v = (float)(rA0 - rint(rA0));
        float4 vq;
        if (fabsf(f0v) > trf) {
            vq = make_float4(0.f, 0.f, 0.f, 0.f);
        } else if (fabsf(f0v) < 6.2e-5f) {
#pragma unroll
            for (int k = 0; k < 4; ++k) {
                double rA = (A0 + (double)k * 32769.0) * invD;
                float ff = (float)(rA - rint(rA));
                float r2;
                if (ff == 0.0f) r2 = 65535.0f;
                else {
                    float s, c2;
                    __sincosf((float)M_PI * ff, &s, &c2);
                    r2 = c2 * __builtin_amdgcn_rcpf(s);
                }
                ((float*)&vq)[k] = ((k & 1) ? Cn : Cp) * r2;
            }
        } else {
            float s, c2;
            __sincosf((float)M_PI * f0v, &s, &c2);
            vq.x = Cp * (c2 * __builtin_amdgcn_rcpf(s));
            float s1 = fmaf(c2, sd, s);
            float c1 = fmaf(-s, sd, c2);
            vq.y = Cn * (c1 * __builtin_amdgcn_rcpf(s1));
            float s2 = fmaf(c1, sd, s1);
            float cc2 = fmaf(-s1, sd, c1);
            vq.z = Cp * (cc2 * __builtin_amdgcn_rcpf(s2));
            float s3 = fmaf(cc2, sd, s2);
            float c3 = fmaf(-s2, sd, cc2);
            vq.w = Cn * (c3 * __builtin_amdgcn_rcpf(s3));
        }
        *(float4*)(hr + 4 * k4) = vq;
    }
}

// ---------------------------------------------------------------- scheduler
// 1-block kernel (needs ALL marr). Also zeroes out[0].
__global__ __launch_bounds__(256) void k_sched(const int* __restrict__ marr,
                                               int* __restrict__ list,
                                               int* __restrict__ cnt,
                                               int nslab,
                                               float* __restrict__ out) {
    __shared__ int scnt[64];                   // (b, region) counters
    __shared__ int total;
    const int tid = threadIdx.x;
    if (tid == 0) out[0] = 0.0f;
    if (tid < 64) scnt[tid] = 0;
    if (tid == 0) total = 0;
    __syncthreads();
    const int RT8 = RTRUNC + 8;
    for (int bf = tid; bf < NB * NFRAMES; bf += 256) {
        int b = bf / NFRAMES;
        int m = marr[bf];
        int p = (int)rint((double)m * (32768.0 / 32769.0));
        int lo = p - RT8;        if (lo < 0) lo = 0;
        int hi = p + RT8 + 511;  if (hi > N_SAMP - 1) hi = N_SAMP - 1;
        int r0 = lo >> 11, r1 = hi >> 11;
        for (int r = r0; r <= r1; ++r) {
            int bc = (b << 4) | r;
            int s = atomicAdd(&scnt[bc], 1);
            int k = atomicAdd(&total, 1);
            list[k] = (bf << 16) | (r << 8) | s;
        }
    }
    __syncthreads();
    int n = total;
    for (int k = tid; k < n; k += 256) {       // whole-region atomic fallback
        int v = list[k];
        int bf = (v >> 16) & 0x3fff;
        int r = (v >> 8) & 15;
        int b = bf / NFRAMES;
        if (scnt[(b << 4) | r] > nslab) list[k] = v | (1 << 30);
    }
    if (tid == 0) {
        int mx = 0;
        for (int i = 0; i < 64; ++i) mx = (scnt[i] > mx) ? scnt[i] : mx;
        cnt[0] = n;
        cnt[1] = (mx > nslab) ? nslab : mx;
    }
}

// ---------------------------------------------------------------- kernel D
// One 2048-output region per list entry. R24 conv: period-5 rolling window
// with ds_read issued 2 groups (~128cy issue) before first use (vs 1 group
// = 64cy in R3 — under the ~120cy LDS latency). NO per-group predication
// (R6's mistake). Bounds rounded to 5; extra groups multiply exact-0.0f h
// blocks (same established-safe class as R3's round-to-3). All LDS reads
// in [0,639]; wc index capped <= 127.
#define LDB(nn) (*(const float4*)(s_h + 4 * SW(nn)))

__global__ __launch_bounds__(256, 8) void k_shift_acc(const float* __restrict__ wf,
                                                      const int* __restrict__ marr,
                                                      const int* __restrict__ list,
                                                      const int* __restrict__ cnt,
                                                      const float* __restrict__ hbuf,
                                                      float* __restrict__ part,
                                                      int slabmask) {
    __shared__ __align__(16) float s_h[2560];    // 10240 B: 8 blk/CU
    const int tid = threadIdx.x;
    const int Lt  = 2 * tid;
    const int Ltw = (tid >> 6) * 128;            // wave-uniform base block
    const int n   = cnt[0];

    for (int se = blockIdx.x; se < n; se += gridDim.x) {
        int v     = list[se];
        int bf    = (v >> 16) & 0x3fff;
        int r     = (v >> 8) & 15;
        int slot  = v & 255;
        int isat  = (v >> 30) & 1;
        int b     = bf / NFRAMES;
        int t0s   = r << 11;                     // this entry's 2048 outputs
        const float4* __restrict__ wc = (const float4*)(wf + bf * 512);

        int m  = marr[bf];
        int pr = (int)rint((double)m * (32768.0 / 32769.0));
        int jlo = pr - (RTRUNC + 8); if (jlo < -512) jlo = -512; jlo &= ~3;
        int kb0 = ((t0s - 512) - jlo) >> 2;      // both multiples of 4
        const float4* __restrict__ hb = (const float4*)(hbuf + (size_t)bf * HW);

        __syncthreads();                          // prior entry's LDS reads done
        for (int e4 = tid; e4 < 640; e4 += 256) {
            int kb = kb0 + e4;
            float4 vq = (kb >= 0 && kb < 776) ? hb[kb]
                                              : make_float4(0.f, 0.f, 0.f, 0.f);
            *(float4*)(s_h + 4 * SW(e4)) = vq;
        }
        __syncthreads();

        // nonzero coeff block range [blo,bhi] (blocks of 4 floats in s_h)
        int blo = (pr - (RTRUNC + 8) - (t0s - 512)) >> 2;
        int bhi = (pr + (RTRUNC + 8) - (t0s - 512)) >> 2;
        if (blo < 0) blo = 0;
        if (bhi > 639) bhi = 639;

        float4 acc0 = make_float4(0.f, 0.f, 0.f, 0.f);
        float4 acc1 = acc0;

        // group g uses coeff blocks {Lt+127-g .. Lt+129-g}; wave covers
        // Lt in [Ltw, Ltw+126] -> active groups [gmin, gmax]
        int gmin = Ltw + 127 - bhi; if (gmin < 0) gmin = 0;
        int gmax = Ltw + 255 - blo; if (gmax > 127) gmax = 127;
        if (gmin <= gmax) {
            int gb0 = (gmin / 5) * 5;                    // <= 125
            float4 s1v = LDB(Lt + 126 - gb0);
            float4 s2v = LDB(Lt + 127 - gb0);
            float4 s3v = LDB(Lt + 128 - gb0);
            float4 s4v = LDB(Lt + 129 - gb0);
            float4 s0v = s1v;                            // init'd in 1st iter
            int gend = (gmax < 120) ? gmax : 120;        // 5-blk cap: g<=124
            for (int gb = gb0; gb <= gend; gb += 5) {
                float4 t0 = LDB(Lt + 125 - gb);          // used at g=gb+2
                { const float4 c = wc[gb];     FMA4(acc0, s2v, s3v); FMA4(acc1, s3v, s4v); }
                s0v = t0;
                float4 t1 = LDB(Lt + 124 - gb);          // used at g=gb+3
                { const float4 c = wc[gb + 1]; FMA4(acc0, s1v, s2v); FMA4(acc1, s2v, s3v); }
                s4v = t1;
                float4 t2 = LDB(Lt + 123 - gb);          // used at g=gb+4
                { const float4 c = wc[gb + 2]; FMA4(acc0, s0v, s1v); FMA4(acc1, s1v, s2v); }
                s3v = t2;
                float4 t3 = LDB(Lt + 122 - gb);          // used at g=gb+5
                { const float4 c = wc[gb + 3]; FMA4(acc0, s4v, s0v); FMA4(acc1, s0v, s1v); }
                s2v = t3;
                float4 t4 = LDB(Lt + 121 - gb);          // used at g=gb+6
                { const float4 c = wc[gb + 4]; FMA4(acc0, s3v, s4v); FMA4(acc1, s4v, s0v); }
                s1v = t4;
            }
            if (gmax >= 125) {                           // tail groups 125..127
                float4 t0 = LDB(Lt);                     // used at g=127
                { const float4 c = wc[125]; FMA4(acc0, s2v, s3v); FMA4(acc1, s3v, s4v); }
                s0v = t0;
                { const float4 c = wc[126]; FMA4(acc0, s1v, s2v); FMA4(acc1, s2v, s3v); }
                { const float4 c = wc[127]; FMA4(acc0, s0v, s1v); FMA4(acc1, s1v, s2v); }
            }
        }

        int slab = slot & slabmask;
        float* ob = part + (size_t)slab * (NB * N_SAMP) + b * N_SAMP + t0s;
        if (!isat) {
            *(float4*)(ob + 8 * tid)     = acc0;
            *(float4*)(ob + 8 * tid + 4) = acc1;
        } else {
            float* p0 = ob + 8 * tid;
            atomicAdd(p0 + 0, acc0.x); atomicAdd(p0 + 1, acc0.y);
            atomicAdd(p0 + 2, acc0.z); atomicAdd(p0 + 3, acc0.w);
            atomicAdd(p0 + 4, acc1.x); atomicAdd(p0 + 5, acc1.y);
            atomicAdd(p0 + 6, acc1.z); atomicAdd(p0 + 7, acc1.w);
        }
    }
}

// ---------------------------------------------------------------- kernel E
__global__ __launch_bounds__(256) void k_mse(const float* __restrict__ part,
                                             const float* __restrict__ tgt,
                                             float* __restrict__ out,
                                             const int* __restrict__ cnt,
                                             int nslab) {
    __shared__ float sred[4];
    int e = blockIdx.x * 256 + threadIdx.x;
    int ng = cnt[1];
    if (ng > nslab) ng = nslab;
    float s0 = 0.f, s1 = 0.f, s2 = 0.f, s3 = 0.f;
    int g = 0;
    for (; g + 4 <= ng; g += 4) {
        s0 += part[(size_t)(g + 0) * (NB * N_SAMP) + e];
        s1 += part[(size_t)(g + 1) * (NB * N_SAMP) + e];
        s2 += part[(size_t)(g + 2) * (NB * N_SAMP) + e];
        s3 += part[(size_t)(g + 3) * (NB * N_SAMP) + e];
    }
    for (; g < ng; ++g)
        s0 += part[(size_t)g * (NB * N_SAMP) + e];
    float s = (s0 + s1) + (s2 + s3);
    float d = s - tgt[e];
    float v = d * d;
#pragma unroll
    for (int off = 32; off > 0; off >>= 1) v += __shfl_down(v, off, 64);
    int lane = threadIdx.x & 63, wid = threadIdx.x >> 6;
    if (lane == 0) sred[wid] = v;
    __syncthreads();
    if (threadIdx.x == 0) {
        float sm = sred[0] + sred[1] + sred[2] + sred[3];
        atomicAdd(out, sm * (1.0f / 131072.0f));
    }
}

// ---------------------------------------------------------------- launch
extern "C" void kernel_launch(void* const* d_in, const int* in_sizes, int n_in,
                              void* d_out, int out_size, void* d_ws, size_t ws_size,
                              hipStream_t stream) {
    const float* recon = (const float*)d_in[0];
    const float* tgt   = (const float*)d_in[1];
    float* out = (float*)d_out;
    float* W   = (float*)d_ws;

    float*     wf   = W + WS_WF;
    _Float16*  wfh  = (_Float16*)(W + WS_WFH);
    float*     pv   = W + WS_PV;
    int*       marr = (int*)(W + WS_M);
    int*       cnt  = (int*)(W + WS_CNT);
    int*       list = (int*)(W + WS_LIST);
    float*     hbuf = W + WS_H;
    float*     part = W + WS_PART;

    int nslab = NSLAB;
    while (nslab > 1 &&
           ((size_t)WS_PART + (size_t)nslab * NB * N_SAMP) * sizeof(float) > ws_size)
        nslab >>= 1;

    k_wf<<<1024, 256, 0, stream>>>(recon, wf, wfh, part, nslab);
    k_argmax_mfma<<<1024, 256, 0, stream>>>(tgt, wfh, pv);
    k_vmax_coef<<<NB * NFRAMES, 256, 0, stream>>>(tgt, wf, pv, marr, hbuf);
    k_sched<<<1, 256, 0, stream>>>(marr, list, cnt, nslab, out);
    k_shift_acc<<<2048, 256, 0, stream>>>(wf, marr, list, cnt, hbuf, part, nslab - 1);
    k_mse<<<512, 256, 0, stream>>>(part, tgt, out, cnt, nslab);
}